// Round 9
// baseline (269.302 us; speedup 1.0000x reference)
//
#include <hip/hip_runtime.h>

#define TT 4096
#define CCH 768
#define HH 64
#define BBA 8
#define MROWS (BBA*TT)   // 32768
#define NCHUNK2 144      // chunks per batch, 128-query tiles, nch = qt/4+1

typedef __attribute__((ext_vector_type(8))) short short8;
typedef __attribute__((ext_vector_type(4))) float floatx4;
#if __has_builtin(__builtin_amdgcn_cvt_pk_bf16_f32)
typedef __attribute__((ext_vector_type(2))) __bf16 bf16x2;
#endif

__device__ inline ushort f2bf(float f) {
    union { float f; unsigned u; } v; v.f = f;
    unsigned r = v.u + 0x7fffu + ((v.u >> 16) & 1u);   // RNE
    return (ushort)(r >> 16);
}

__device__ inline float bf2f(ushort h) {
    union { unsigned u; float f; } v; v.u = ((unsigned)h) << 16;
    return v.f;
}

__device__ inline unsigned pk_bf16(float a, float b) {
#if __has_builtin(__builtin_amdgcn_cvt_pk_bf16_f32)
    union { bf16x2 v; unsigned u; } cv;
    cv.v = __builtin_amdgcn_cvt_pk_bf16_f32(a, b);
    return cv.u;
#else
    union { float f; unsigned u; } x, y; x.f = a; y.f = b;
    unsigned ra = x.u + 0x7fffu + ((x.u >> 16) & 1u);
    unsigned rb = y.u + 0x7fffu + ((y.u >> 16) & 1u);
    return (ra >> 16) | (rb & 0xffff0000u);
#endif
}

__device__ inline float fast_exp2(float x) {
#if __has_builtin(__builtin_amdgcn_exp2f)
    return __builtin_amdgcn_exp2f(x);
#else
    return exp2f(x);
#endif
}

// ---- Kernel 1: Wt[3][64][768] bf16, n-major, via LDS transpose.
// Wq PRE-SCALED by 768^-0.5 * log2(e): QK^T emerges in exp2 domain.
__global__ __launch_bounds__(256) void wt_kernel(const float* __restrict__ Wq,
                                                 const float* __restrict__ Wk,
                                                 const float* __restrict__ Wv,
                                                 ushort* __restrict__ wt) {
    __shared__ float tile[64][65];
    const int m = blockIdx.x / 12, kt = blockIdx.x % 12;
    const float* W = (m == 0) ? Wq : (m == 1) ? Wk : Wv;
    const float scl = (m == 0) ? 0.052058773f : 1.0f;   // 768^-0.5 * log2(e)
    const int n = threadIdx.x & 63, r0 = threadIdx.x >> 6;
#pragma unroll
    for (int i = 0; i < 16; ++i) {
        int k = r0 * 16 + i;
        tile[k][n] = W[(kt * 64 + k) * 64 + n] * scl;
    }
    __syncthreads();
    const int k2 = threadIdx.x & 63, n2 = threadIdx.x >> 6;
#pragma unroll
    for (int i = 0; i < 16; ++i) {
        int nn = n2 * 16 + i;
        wt[(m * 64 + nn) * 768 + kt * 64 + k2] = f2bf(tile[k2][nn]);
    }
}

// ---- Kernel 2: QKV projection v7 (r7 best: 512 blocks x 64 rows, BK=64) ----
__global__ __launch_bounds__(256) void proj_kernel(const float* __restrict__ x,
                                                   const ushort* __restrict__ wt,
                                                   ushort* __restrict__ qb,
                                                   ushort* __restrict__ kb,
                                                   ushort* __restrict__ vtg) {
    __shared__ ushort xs[64 * 72];      // 64 rows x 64 k (bf16)
    __shared__ ushort ws[192 * 72];     // 192 cols x 64 k (bf16)
    const int tid = threadIdx.x;
    const int w = tid >> 6, lane = tid & 63, c = lane & 15, qd = lane >> 4;
    const int rbase = blockIdx.x * 64;
    const int sr = tid >> 2;            // staging row 0..63
    const int sq = tid & 3;             // staging quarter (16 k each)

    floatx4 acc[12];
#pragma unroll
    for (int nt = 0; nt < 12; ++nt) acc[nt] = (floatx4){0.f, 0.f, 0.f, 0.f};

    const float*  xsrc = &x[(size_t)(rbase + sr) * CCH + sq * 16];
    const ushort* wsrc0 = &wt[(size_t)(0 * 64 + sr) * CCH + sq * 16];
    const ushort* wsrc1 = &wt[(size_t)(1 * 64 + sr) * CCH + sq * 16];
    const ushort* wsrc2 = &wt[(size_t)(2 * 64 + sr) * CCH + sq * 16];

    float4 xr[4];
    short8 wr[6];
    xr[0] = *(const float4*)&xsrc[0];  xr[1] = *(const float4*)&xsrc[4];
    xr[2] = *(const float4*)&xsrc[8];  xr[3] = *(const float4*)&xsrc[12];
    wr[0] = *(const short8*)&wsrc0[0]; wr[1] = *(const short8*)&wsrc0[8];
    wr[2] = *(const short8*)&wsrc1[0]; wr[3] = *(const short8*)&wsrc1[8];
    wr[4] = *(const short8*)&wsrc2[0]; wr[5] = *(const short8*)&wsrc2[8];

    for (int kc = 0; kc < CCH; kc += 64) {
        uint4 s0, s1;
        s0.x = pk_bf16(xr[0].x, xr[0].y); s0.y = pk_bf16(xr[0].z, xr[0].w);
        s0.z = pk_bf16(xr[1].x, xr[1].y); s0.w = pk_bf16(xr[1].z, xr[1].w);
        s1.x = pk_bf16(xr[2].x, xr[2].y); s1.y = pk_bf16(xr[2].z, xr[2].w);
        s1.z = pk_bf16(xr[3].x, xr[3].y); s1.w = pk_bf16(xr[3].z, xr[3].w);
        *(uint4*)&xs[sr * 72 + sq * 16]     = s0;
        *(uint4*)&xs[sr * 72 + sq * 16 + 8] = s1;
        *(short8*)&ws[(0 * 64 + sr) * 72 + sq * 16]     = wr[0];
        *(short8*)&ws[(0 * 64 + sr) * 72 + sq * 16 + 8] = wr[1];
        *(short8*)&ws[(1 * 64 + sr) * 72 + sq * 16]     = wr[2];
        *(short8*)&ws[(1 * 64 + sr) * 72 + sq * 16 + 8] = wr[3];
        *(short8*)&ws[(2 * 64 + sr) * 72 + sq * 16]     = wr[4];
        *(short8*)&ws[(2 * 64 + sr) * 72 + sq * 16 + 8] = wr[5];
        __syncthreads();
        if (kc + 64 < CCH) {
            xr[0] = *(const float4*)&xsrc[kc + 64];
            xr[1] = *(const float4*)&xsrc[kc + 68];
            xr[2] = *(const float4*)&xsrc[kc + 72];
            xr[3] = *(const float4*)&xsrc[kc + 76];
            wr[0] = *(const short8*)&wsrc0[kc + 64]; wr[1] = *(const short8*)&wsrc0[kc + 72];
            wr[2] = *(const short8*)&wsrc1[kc + 64]; wr[3] = *(const short8*)&wsrc1[kc + 72];
            wr[4] = *(const short8*)&wsrc2[kc + 64]; wr[5] = *(const short8*)&wsrc2[kc + 72];
        }
        short8 a0 = *(const short8*)&xs[(w * 16 + c) * 72 + qd * 8];
        short8 a1 = *(const short8*)&xs[(w * 16 + c) * 72 + 32 + qd * 8];
#pragma unroll
        for (int nt = 0; nt < 12; ++nt) {
            short8 b0 = *(const short8*)&ws[(nt * 16 + c) * 72 + qd * 8];
            short8 b1 = *(const short8*)&ws[(nt * 16 + c) * 72 + 32 + qd * 8];
            acc[nt] = __builtin_amdgcn_mfma_f32_16x16x32_bf16(a0, b0, acc[nt], 0, 0, 0);
            acc[nt] = __builtin_amdgcn_mfma_f32_16x16x32_bf16(a1, b1, acc[nt], 0, 0, 0);
        }
        __syncthreads();
    }
#pragma unroll
    for (int nt = 0; nt < 8; ++nt) {
        int ncol = nt * 16 + c;
        ushort* dst = (ncol < 64) ? qb : kb;
        int h = ncol & 63;
#pragma unroll
        for (int r = 0; r < 4; ++r) {
            int rg = rbase + w * 16 + qd * 4 + r;
            dst[(size_t)rg * 64 + h] = f2bf(acc[nt][r]);
        }
    }
    const int bb = rbase >> 12;
    const int tbase = (rbase & 4095) + w * 16 + qd * 4;
#pragma unroll
    for (int nt = 8; nt < 12; ++nt) {
        int h = (nt - 8) * 16 + c;
        uint2 val;
        val.x = pk_bf16(acc[nt][0], acc[nt][1]);
        val.y = pk_bf16(acc[nt][2], acc[nt][3]);
        *(uint2*)&vtg[((size_t)(bb * 64 + h)) * 4096 + tbase] = val;
    }
}

// ---- Kernel 3: flash attention v2 — 128-QUERY tiles (2 subtiles/wave),
// fixed-reference exp2 softmax (m=0), Q pre-scaled, chunked key-split. ----
__global__ __launch_bounds__(256) void attn_kernel(const ushort* __restrict__ qb,
                                                   const ushort* __restrict__ kb,
                                                   const ushort* __restrict__ vtg,
                                                   float* __restrict__ out,
                                                   ushort* __restrict__ Opart,
                                                   float* __restrict__ Ol) {
    __shared__ ushort Ks[64 * 72];      // [key][dim]
    __shared__ ushort Vt[64 * 72];      // [dim][key]
    __shared__ ushort Pl[4][2048];      // per wave: 2 subtiles x 16q x 64k
    const int tid = threadIdx.x;
    const int w = tid >> 6, lane = tid & 63, c = lane & 15, qd = lane >> 4;
    const int bx = blockIdx.x;
    const int b = bx & 7, craw = bx >> 3;

    // decode chunk: groups g=0..7, qt128 in [4g,4g+4), nch=g+1, group start s=2g(g+1)
    const int cix = (NCHUNK2 - 1) - craw;   // big chunks dispatch first
    int g = 0;
#pragma unroll
    for (int t = 1; t < 8; ++t) if (cix >= 2 * t * (t + 1)) g = t;
    const int nch = g + 1;
    const int d = cix - 2 * g * (g + 1);
    const int qt = 4 * g + d / nch;          // 128-query tile index, 0..31
    const int chunk = d - (d / nch) * nch;
    const int n = 2 * qt + 2;                // 64-key tiles in causal range
    const int kbeg = chunk * n / nch;
    const int kend = (chunk + 1) * n / nch;
    const bool direct = (nch == 1);
    const int qbase = qt * 128;

    // Q fragments: wave owns queries qbase + w*32 + sub*16 + c
    short8 qf[2][2];
#pragma unroll
    for (int sub = 0; sub < 2; ++sub) {
        const size_t gq = (size_t)(b * TT + qbase + w * 32 + sub * 16 + c);
        qf[sub][0] = *(const short8*)&qb[gq * 64 + qd * 8];
        qf[sub][1] = *(const short8*)&qb[gq * 64 + 32 + qd * 8];
    }
    floatx4 o[2][4];
#pragma unroll
    for (int sub = 0; sub < 2; ++sub)
#pragma unroll
        for (int nt = 0; nt < 4; ++nt) o[sub][nt] = (floatx4){0.f, 0.f, 0.f, 0.f};
    float lsum[2] = {0.f, 0.f};

    const int sr = tid >> 2;            // K staging: key row
    const int sk = (tid & 3) * 16;      // K staging: dim offset
    const ushort* kbb = &kb[(size_t)(b * TT) * 64];
    const ushort* vbb = &vtg[(size_t)(b * 64) * 4096];

    short8 k0, k1, v0, v1;
    {
        const ushort* srcK = &kbb[((size_t)(kbeg * 64 + sr)) * 64 + sk];
        k0 = *(const short8*)srcK; k1 = *(const short8*)(srcK + 8);
        const ushort* srcV = &vbb[(size_t)sr * 4096 + kbeg * 64 + sk];
        v0 = *(const short8*)srcV; v1 = *(const short8*)(srcV + 8);
    }

    for (int kt = kbeg; kt < kend; ++kt) {
        __syncthreads();
        *(short8*)&Ks[sr * 72 + sk] = k0;
        *(short8*)&Ks[sr * 72 + sk + 8] = k1;
        *(short8*)&Vt[sr * 72 + sk] = v0;
        *(short8*)&Vt[sr * 72 + sk + 8] = v1;
        __syncthreads();
        if (kt + 1 < kend) {
            const ushort* srcK = &kbb[((size_t)((kt + 1) * 64 + sr)) * 64 + sk];
            k0 = *(const short8*)srcK; k1 = *(const short8*)(srcK + 8);
            const ushort* srcV = &vbb[(size_t)sr * 4096 + (kt + 1) * 64 + sk];
            v0 = *(const short8*)srcV; v1 = *(const short8*)(srcV + 8);
        }
        // S^T for both subtiles; K frags shared
        floatx4 st[2][4];
#pragma unroll
        for (int mt = 0; mt < 4; ++mt) {
            short8 kf0 = *(const short8*)&Ks[(mt * 16 + c) * 72 + qd * 8];
            short8 kf1 = *(const short8*)&Ks[(mt * 16 + c) * 72 + 32 + qd * 8];
            st[0][mt] = (floatx4){0.f, 0.f, 0.f, 0.f};
            st[0][mt] = __builtin_amdgcn_mfma_f32_16x16x32_bf16(kf0, qf[0][0], st[0][mt], 0, 0, 0);
            st[0][mt] = __builtin_amdgcn_mfma_f32_16x16x32_bf16(kf1, qf[0][1], st[0][mt], 0, 0, 0);
            st[1][mt] = (floatx4){0.f, 0.f, 0.f, 0.f};
            st[1][mt] = __builtin_amdgcn_mfma_f32_16x16x32_bf16(kf0, qf[1][0], st[1][mt], 0, 0, 0);
            st[1][mt] = __builtin_amdgcn_mfma_f32_16x16x32_bf16(kf1, qf[1][1], st[1][mt], 0, 0, 0);
        }
        // mask (last two tiles only) + exp2 + pack to Pl
        const bool domask = (kt >= 2 * qt);     // block-uniform
#pragma unroll
        for (int sub = 0; sub < 2; ++sub) {
            const int thr = qbase + w * 32 + sub * 16 + c;
            float ls = 0.f;
#pragma unroll
            for (int mt = 0; mt < 4; ++mt) {
                float e[4];
#pragma unroll
                for (int r = 0; r < 4; ++r) {
                    float v = st[sub][mt][r];
                    if (domask) {
                        int kl = kt * 64 + mt * 16 + qd * 4 + r;
                        if (kl > thr) v = -1e30f;
                    }
                    e[r] = fast_exp2(v);
                    ls += e[r];
                }
                uint2 pk;
                pk.x = pk_bf16(e[0], e[1]);
                pk.y = pk_bf16(e[2], e[3]);
                int gg = 2 * mt + (qd >> 1);
                int off = sub * 1024 + c * 64 + ((gg ^ (c & 7)) << 3) + ((qd & 1) << 2);
                *(uint2*)&Pl[w][off] = pk;
            }
            lsum[sub] += ls;
        }
        // PV: V frags shared across subtiles
        short8 pf00 = *(const short8*)&Pl[w][c * 64 + (((qd) ^ (c & 7)) << 3)];
        short8 pf01 = *(const short8*)&Pl[w][c * 64 + (((4 + qd) ^ (c & 7)) << 3)];
        short8 pf10 = *(const short8*)&Pl[w][1024 + c * 64 + (((qd) ^ (c & 7)) << 3)];
        short8 pf11 = *(const short8*)&Pl[w][1024 + c * 64 + (((4 + qd) ^ (c & 7)) << 3)];
#pragma unroll
        for (int nt = 0; nt < 4; ++nt) {
            short8 vf0 = *(const short8*)&Vt[(nt * 16 + c) * 72 + qd * 8];
            short8 vf1 = *(const short8*)&Vt[(nt * 16 + c) * 72 + 32 + qd * 8];
            o[0][nt] = __builtin_amdgcn_mfma_f32_16x16x32_bf16(pf00, vf0, o[0][nt], 0, 0, 0);
            o[0][nt] = __builtin_amdgcn_mfma_f32_16x16x32_bf16(pf01, vf1, o[0][nt], 0, 0, 0);
            o[1][nt] = __builtin_amdgcn_mfma_f32_16x16x32_bf16(pf10, vf0, o[1][nt], 0, 0, 0);
            o[1][nt] = __builtin_amdgcn_mfma_f32_16x16x32_bf16(pf11, vf1, o[1][nt], 0, 0, 0);
        }
    }

    // post-loop l reductions across key quads
#pragma unroll
    for (int sub = 0; sub < 2; ++sub) {
        lsum[sub] += __shfl_xor(lsum[sub], 16);
        lsum[sub] += __shfl_xor(lsum[sub], 32);
    }

    if (direct) {
#pragma unroll
        for (int sub = 0; sub < 2; ++sub)
#pragma unroll
            for (int r = 0; r < 4; ++r) {
                float lr = __shfl(lsum[sub], qd * 4 + r);
                float inv = 1.f / lr;
                size_t rowg = (size_t)(b * TT) + qbase + w * 32 + sub * 16 + qd * 4 + r;
#pragma unroll
                for (int nt = 0; nt < 4; ++nt)
                    out[rowg * 64 + nt * 16 + c] = o[sub][nt][r] * inv;
            }
    } else {
        const int slot = b * NCHUNK2 + cix;
        ushort* Od = Opart + (size_t)slot * 8192;
#pragma unroll
        for (int sub = 0; sub < 2; ++sub)
#pragma unroll
            for (int r = 0; r < 4; ++r) {
                int row = w * 32 + sub * 16 + qd * 4 + r;
#pragma unroll
                for (int nt = 0; nt < 4; ++nt)
                    Od[row * 64 + nt * 16 + c] = f2bf(o[sub][nt][r]);
            }
        if (qd == 0) {
            Ol[(size_t)slot * 128 + w * 32 + c] = lsum[0];
            Ol[(size_t)slot * 128 + w * 32 + 16 + c] = lsum[1];
        }
    }
}

// ---- Kernel 4: combine partials for qt128 >= 4 (plain sums, m=0) ----
__global__ __launch_bounds__(256) void combine_kernel(const ushort* __restrict__ Opart,
                                                      const float* __restrict__ Ol,
                                                      float* __restrict__ out) {
    const int b = blockIdx.x & 7;
    const int qq = 4 + (blockIdx.x >> 3);   // 4..31
    const int g = qq >> 2;                  // 1..7
    const int nch = g + 1;
    const int c0 = 2 * g * (g + 1) + (qq - 4 * g) * nch;
    const size_t slot0 = (size_t)(b * NCHUNK2 + c0);
    const int t = threadIdx.x;
    const int col = t & 63, r0 = t >> 6;

    for (int rr = 0; rr < 32; ++rr) {
        int row = (rr << 2) + r0;
        float S = 0.f, A = 0.f;
        for (int i = 0; i < nch; ++i) {
            S += Ol[(slot0 + i) * 128 + row];
            A += bf2f(Opart[(slot0 + i) * 8192 + row * 64 + col]);
        }
        out[((size_t)(b * TT) + qq * 128 + row) * 64 + col] = A / S;
    }
}

extern "C" void kernel_launch(void* const* d_in, const int* in_sizes, int n_in,
                              void* d_out, int out_size, void* d_ws, size_t ws_size,
                              hipStream_t stream) {
    const float* x  = (const float*)d_in[0];
    const float* Wk = (const float*)d_in[1];
    const float* Wq = (const float*)d_in[2];
    const float* Wv = (const float*)d_in[3];
    float* out = (float*)d_out;

    // ws: q,k bf16 [32768][64]; v^T bf16 [8][64][4096]; Wt; bf16 partials + l
    ushort* qbuf = (ushort*)d_ws;
    ushort* kbuf = qbuf + (size_t)MROWS * 64;
    ushort* vbuf = kbuf + (size_t)MROWS * 64;
    ushort* wt   = vbuf + (size_t)MROWS * 64;
    const size_t base = (size_t)MROWS * 64 * 3 * 2 + (size_t)3 * 64 * CCH * 2;  // 12,877,824
    ushort* Opart = (ushort*)((char*)d_ws + base);
    float*  Ol    = (float*)((char*)d_ws + base + (size_t)BBA * NCHUNK2 * 8192 * 2);
    // need = base + 18.87 MB + 0.59 MB ~= 32.3 MB (assumed available, as in prior rounds)

    wt_kernel<<<36, 256, 0, stream>>>(Wq, Wk, Wv, wt);
    proj_kernel<<<MROWS / 64, 256, 0, stream>>>(x, wt, qbuf, kbuf, vbuf);
    attn_kernel<<<BBA * NCHUNK2, 256, 0, stream>>>(qbuf, kbuf, vbuf, out, Opart, Ol);
    combine_kernel<<<BBA * 28, 256, 0, stream>>>(Opart, Ol, out);
}

// Round 10
// 210.102 us; speedup vs baseline: 1.2818x; 1.2818x over previous
//
#include <hip/hip_runtime.h>

#define TT 4096
#define CCH 768
#define HH 64
#define BBA 8
#define MROWS (BBA*TT)   // 32768
#define NCHUNK2 144      // chunks per batch, 128-query tiles, nch = qt/4+1

typedef __attribute__((ext_vector_type(8))) short short8;
typedef __attribute__((ext_vector_type(4))) float floatx4;
#if __has_builtin(__builtin_amdgcn_cvt_pk_bf16_f32)
typedef __attribute__((ext_vector_type(2))) __bf16 bf16x2;
#endif

__device__ inline ushort f2bf(float f) {
    union { float f; unsigned u; } v; v.f = f;
    unsigned r = v.u + 0x7fffu + ((v.u >> 16) & 1u);   // RNE
    return (ushort)(r >> 16);
}

__device__ inline float bf2f(ushort h) {
    union { unsigned u; float f; } v; v.u = ((unsigned)h) << 16;
    return v.f;
}

__device__ inline unsigned pk_bf16(float a, float b) {
#if __has_builtin(__builtin_amdgcn_cvt_pk_bf16_f32)
    union { bf16x2 v; unsigned u; } cv;
    cv.v = __builtin_amdgcn_cvt_pk_bf16_f32(a, b);
    return cv.u;
#else
    union { float f; unsigned u; } x, y; x.f = a; y.f = b;
    unsigned ra = x.u + 0x7fffu + ((x.u >> 16) & 1u);
    unsigned rb = y.u + 0x7fffu + ((y.u >> 16) & 1u);
    return (ra >> 16) | (rb & 0xffff0000u);
#endif
}

__device__ inline float fast_exp2(float x) {
#if __has_builtin(__builtin_amdgcn_exp2f)
    return __builtin_amdgcn_exp2f(x);
#else
    return exp2f(x);
#endif
}

// ---- Kernel 1: Wt[3][64][768] bf16, n-major, via LDS transpose.
// Wq PRE-SCALED by 768^-0.5 * log2(e): QK^T emerges in exp2 domain.
__global__ __launch_bounds__(256) void wt_kernel(const float* __restrict__ Wq,
                                                 const float* __restrict__ Wk,
                                                 const float* __restrict__ Wv,
                                                 ushort* __restrict__ wt) {
    __shared__ float tile[64][65];
    const int m = blockIdx.x / 12, kt = blockIdx.x % 12;
    const float* W = (m == 0) ? Wq : (m == 1) ? Wk : Wv;
    const float scl = (m == 0) ? 0.052058773f : 1.0f;   // 768^-0.5 * log2(e)
    const int n = threadIdx.x & 63, r0 = threadIdx.x >> 6;
#pragma unroll
    for (int i = 0; i < 16; ++i) {
        int k = r0 * 16 + i;
        tile[k][n] = W[(kt * 64 + k) * 64 + n] * scl;
    }
    __syncthreads();
    const int k2 = threadIdx.x & 63, n2 = threadIdx.x >> 6;
#pragma unroll
    for (int i = 0; i < 16; ++i) {
        int nn = n2 * 16 + i;
        wt[(m * 64 + nn) * 768 + kt * 64 + k2] = f2bf(tile[k2][nn]);
    }
}

// ---- Kernel 2: QKV projection v7 (r7 best: 512 blocks x 64 rows, BK=64) ----
__global__ __launch_bounds__(256) void proj_kernel(const float* __restrict__ x,
                                                   const ushort* __restrict__ wt,
                                                   ushort* __restrict__ qb,
                                                   ushort* __restrict__ kb,
                                                   ushort* __restrict__ vtg) {
    __shared__ ushort xs[64 * 72];      // 64 rows x 64 k (bf16)
    __shared__ ushort ws[192 * 72];     // 192 cols x 64 k (bf16)
    const int tid = threadIdx.x;
    const int w = tid >> 6, lane = tid & 63, c = lane & 15, qd = lane >> 4;
    const int rbase = blockIdx.x * 64;
    const int sr = tid >> 2;            // staging row 0..63
    const int sq = tid & 3;             // staging quarter (16 k each)

    floatx4 acc[12];
#pragma unroll
    for (int nt = 0; nt < 12; ++nt) acc[nt] = (floatx4){0.f, 0.f, 0.f, 0.f};

    const float*  xsrc = &x[(size_t)(rbase + sr) * CCH + sq * 16];
    const ushort* wsrc0 = &wt[(size_t)(0 * 64 + sr) * CCH + sq * 16];
    const ushort* wsrc1 = &wt[(size_t)(1 * 64 + sr) * CCH + sq * 16];
    const ushort* wsrc2 = &wt[(size_t)(2 * 64 + sr) * CCH + sq * 16];

    float4 xr[4];
    short8 wr[6];
    xr[0] = *(const float4*)&xsrc[0];  xr[1] = *(const float4*)&xsrc[4];
    xr[2] = *(const float4*)&xsrc[8];  xr[3] = *(const float4*)&xsrc[12];
    wr[0] = *(const short8*)&wsrc0[0]; wr[1] = *(const short8*)&wsrc0[8];
    wr[2] = *(const short8*)&wsrc1[0]; wr[3] = *(const short8*)&wsrc1[8];
    wr[4] = *(const short8*)&wsrc2[0]; wr[5] = *(const short8*)&wsrc2[8];

    for (int kc = 0; kc < CCH; kc += 64) {
        uint4 s0, s1;
        s0.x = pk_bf16(xr[0].x, xr[0].y); s0.y = pk_bf16(xr[0].z, xr[0].w);
        s0.z = pk_bf16(xr[1].x, xr[1].y); s0.w = pk_bf16(xr[1].z, xr[1].w);
        s1.x = pk_bf16(xr[2].x, xr[2].y); s1.y = pk_bf16(xr[2].z, xr[2].w);
        s1.z = pk_bf16(xr[3].x, xr[3].y); s1.w = pk_bf16(xr[3].z, xr[3].w);
        *(uint4*)&xs[sr * 72 + sq * 16]     = s0;
        *(uint4*)&xs[sr * 72 + sq * 16 + 8] = s1;
        *(short8*)&ws[(0 * 64 + sr) * 72 + sq * 16]     = wr[0];
        *(short8*)&ws[(0 * 64 + sr) * 72 + sq * 16 + 8] = wr[1];
        *(short8*)&ws[(1 * 64 + sr) * 72 + sq * 16]     = wr[2];
        *(short8*)&ws[(1 * 64 + sr) * 72 + sq * 16 + 8] = wr[3];
        *(short8*)&ws[(2 * 64 + sr) * 72 + sq * 16]     = wr[4];
        *(short8*)&ws[(2 * 64 + sr) * 72 + sq * 16 + 8] = wr[5];
        __syncthreads();
        if (kc + 64 < CCH) {
            xr[0] = *(const float4*)&xsrc[kc + 64];
            xr[1] = *(const float4*)&xsrc[kc + 68];
            xr[2] = *(const float4*)&xsrc[kc + 72];
            xr[3] = *(const float4*)&xsrc[kc + 76];
            wr[0] = *(const short8*)&wsrc0[kc + 64]; wr[1] = *(const short8*)&wsrc0[kc + 72];
            wr[2] = *(const short8*)&wsrc1[kc + 64]; wr[3] = *(const short8*)&wsrc1[kc + 72];
            wr[4] = *(const short8*)&wsrc2[kc + 64]; wr[5] = *(const short8*)&wsrc2[kc + 72];
        }
        short8 a0 = *(const short8*)&xs[(w * 16 + c) * 72 + qd * 8];
        short8 a1 = *(const short8*)&xs[(w * 16 + c) * 72 + 32 + qd * 8];
#pragma unroll
        for (int nt = 0; nt < 12; ++nt) {
            short8 b0 = *(const short8*)&ws[(nt * 16 + c) * 72 + qd * 8];
            short8 b1 = *(const short8*)&ws[(nt * 16 + c) * 72 + 32 + qd * 8];
            acc[nt] = __builtin_amdgcn_mfma_f32_16x16x32_bf16(a0, b0, acc[nt], 0, 0, 0);
            acc[nt] = __builtin_amdgcn_mfma_f32_16x16x32_bf16(a1, b1, acc[nt], 0, 0, 0);
        }
        __syncthreads();
    }
#pragma unroll
    for (int nt = 0; nt < 8; ++nt) {
        int ncol = nt * 16 + c;
        ushort* dst = (ncol < 64) ? qb : kb;
        int h = ncol & 63;
#pragma unroll
        for (int r = 0; r < 4; ++r) {
            int rg = rbase + w * 16 + qd * 4 + r;
            dst[(size_t)rg * 64 + h] = f2bf(acc[nt][r]);
        }
    }
    const int bb = rbase >> 12;
    const int tbase = (rbase & 4095) + w * 16 + qd * 4;
#pragma unroll
    for (int nt = 8; nt < 12; ++nt) {
        int h = (nt - 8) * 16 + c;
        uint2 val;
        val.x = pk_bf16(acc[nt][0], acc[nt][1]);
        val.y = pk_bf16(acc[nt][2], acc[nt][3]);
        *(uint2*)&vtg[((size_t)(bb * 64 + h)) * 4096 + tbase] = val;
    }
}

// ---- Kernel 3: flash attention v2 — 128-QUERY tiles (2 subtiles/wave),
// fixed-reference exp2 softmax (m=0), Q pre-scaled, chunked key-split. ----
__global__ __launch_bounds__(256) void attn_kernel(const ushort* __restrict__ qb,
                                                   const ushort* __restrict__ kb,
                                                   const ushort* __restrict__ vtg,
                                                   float* __restrict__ out,
                                                   ushort* __restrict__ Opart,
                                                   float* __restrict__ Ol) {
    __shared__ ushort Ks[64 * 72];      // [key][dim]
    __shared__ ushort Vt[64 * 72];      // [dim][key]
    __shared__ ushort Pl[4][2048];      // per wave: 2 subtiles x 16q x 64k
    const int tid = threadIdx.x;
    const int w = tid >> 6, lane = tid & 63, c = lane & 15, qd = lane >> 4;
    const int bx = blockIdx.x;
    const int b = bx & 7, craw = bx >> 3;

    // decode chunk: groups g=0..7, qt128 in [4g,4g+4), nch=g+1, group start s=2g(g+1)
    const int cix = (NCHUNK2 - 1) - craw;   // big chunks dispatch first
    int g = 0;
#pragma unroll
    for (int t = 1; t < 8; ++t) if (cix >= 2 * t * (t + 1)) g = t;
    const int nch = g + 1;
    const int d = cix - 2 * g * (g + 1);
    const int qt = 4 * g + d / nch;          // 128-query tile index, 0..31
    const int chunk = d - (d / nch) * nch;
    const int n = 2 * qt + 2;                // 64-key tiles in causal range
    const int kbeg = chunk * n / nch;
    const int kend = (chunk + 1) * n / nch;
    const bool direct = (nch == 1);
    const int qbase = qt * 128;

    // Q fragments: wave owns queries qbase + w*32 + sub*16 + c
    short8 qf[2][2];
#pragma unroll
    for (int sub = 0; sub < 2; ++sub) {
        const size_t gq = (size_t)(b * TT + qbase + w * 32 + sub * 16 + c);
        qf[sub][0] = *(const short8*)&qb[gq * 64 + qd * 8];
        qf[sub][1] = *(const short8*)&qb[gq * 64 + 32 + qd * 8];
    }
    floatx4 o[2][4];
#pragma unroll
    for (int sub = 0; sub < 2; ++sub)
#pragma unroll
        for (int nt = 0; nt < 4; ++nt) o[sub][nt] = (floatx4){0.f, 0.f, 0.f, 0.f};
    float lsum[2] = {0.f, 0.f};

    const int sr = tid >> 2;            // K staging: key row
    const int sk = (tid & 3) * 16;      // K staging: dim offset
    const ushort* kbb = &kb[(size_t)(b * TT) * 64];
    const ushort* vbb = &vtg[(size_t)(b * 64) * 4096];

    short8 k0, k1, v0, v1;
    {
        const ushort* srcK = &kbb[((size_t)(kbeg * 64 + sr)) * 64 + sk];
        k0 = *(const short8*)srcK; k1 = *(const short8*)(srcK + 8);
        const ushort* srcV = &vbb[(size_t)sr * 4096 + kbeg * 64 + sk];
        v0 = *(const short8*)srcV; v1 = *(const short8*)(srcV + 8);
    }

    for (int kt = kbeg; kt < kend; ++kt) {
        __syncthreads();
        *(short8*)&Ks[sr * 72 + sk] = k0;
        *(short8*)&Ks[sr * 72 + sk + 8] = k1;
        *(short8*)&Vt[sr * 72 + sk] = v0;
        *(short8*)&Vt[sr * 72 + sk + 8] = v1;
        __syncthreads();
        if (kt + 1 < kend) {
            const ushort* srcK = &kbb[((size_t)((kt + 1) * 64 + sr)) * 64 + sk];
            k0 = *(const short8*)srcK; k1 = *(const short8*)(srcK + 8);
            const ushort* srcV = &vbb[(size_t)sr * 4096 + (kt + 1) * 64 + sk];
            v0 = *(const short8*)srcV; v1 = *(const short8*)(srcV + 8);
        }
        // S^T for both subtiles; K frags shared
        floatx4 st[2][4];
#pragma unroll
        for (int mt = 0; mt < 4; ++mt) {
            short8 kf0 = *(const short8*)&Ks[(mt * 16 + c) * 72 + qd * 8];
            short8 kf1 = *(const short8*)&Ks[(mt * 16 + c) * 72 + 32 + qd * 8];
            st[0][mt] = (floatx4){0.f, 0.f, 0.f, 0.f};
            st[0][mt] = __builtin_amdgcn_mfma_f32_16x16x32_bf16(kf0, qf[0][0], st[0][mt], 0, 0, 0);
            st[0][mt] = __builtin_amdgcn_mfma_f32_16x16x32_bf16(kf1, qf[0][1], st[0][mt], 0, 0, 0);
            st[1][mt] = (floatx4){0.f, 0.f, 0.f, 0.f};
            st[1][mt] = __builtin_amdgcn_mfma_f32_16x16x32_bf16(kf0, qf[1][0], st[1][mt], 0, 0, 0);
            st[1][mt] = __builtin_amdgcn_mfma_f32_16x16x32_bf16(kf1, qf[1][1], st[1][mt], 0, 0, 0);
        }
        // mask (last two tiles only) + exp2 + pack to Pl
        const bool domask = (kt >= 2 * qt);     // block-uniform
#pragma unroll
        for (int sub = 0; sub < 2; ++sub) {
            const int thr = qbase + w * 32 + sub * 16 + c;
            float ls = 0.f;
#pragma unroll
            for (int mt = 0; mt < 4; ++mt) {
                float e[4];
#pragma unroll
                for (int r = 0; r < 4; ++r) {
                    float v = st[sub][mt][r];
                    if (domask) {
                        int kl = kt * 64 + mt * 16 + qd * 4 + r;
                        if (kl > thr) v = -1e30f;
                    }
                    e[r] = fast_exp2(v);
                    ls += e[r];
                }
                uint2 pk;
                pk.x = pk_bf16(e[0], e[1]);
                pk.y = pk_bf16(e[2], e[3]);
                int gg = 2 * mt + (qd >> 1);
                int off = sub * 1024 + c * 64 + ((gg ^ (c & 7)) << 3) + ((qd & 1) << 2);
                *(uint2*)&Pl[w][off] = pk;
            }
            lsum[sub] += ls;
        }
        // PV: V frags shared across subtiles
        short8 pf00 = *(const short8*)&Pl[w][c * 64 + (((qd) ^ (c & 7)) << 3)];
        short8 pf01 = *(const short8*)&Pl[w][c * 64 + (((4 + qd) ^ (c & 7)) << 3)];
        short8 pf10 = *(const short8*)&Pl[w][1024 + c * 64 + (((qd) ^ (c & 7)) << 3)];
        short8 pf11 = *(const short8*)&Pl[w][1024 + c * 64 + (((4 + qd) ^ (c & 7)) << 3)];
#pragma unroll
        for (int nt = 0; nt < 4; ++nt) {
            short8 vf0 = *(const short8*)&Vt[(nt * 16 + c) * 72 + qd * 8];
            short8 vf1 = *(const short8*)&Vt[(nt * 16 + c) * 72 + 32 + qd * 8];
            o[0][nt] = __builtin_amdgcn_mfma_f32_16x16x32_bf16(pf00, vf0, o[0][nt], 0, 0, 0);
            o[0][nt] = __builtin_amdgcn_mfma_f32_16x16x32_bf16(pf01, vf1, o[0][nt], 0, 0, 0);
            o[1][nt] = __builtin_amdgcn_mfma_f32_16x16x32_bf16(pf10, vf0, o[1][nt], 0, 0, 0);
            o[1][nt] = __builtin_amdgcn_mfma_f32_16x16x32_bf16(pf11, vf1, o[1][nt], 0, 0, 0);
        }
    }

    // post-loop l reductions across key quads
#pragma unroll
    for (int sub = 0; sub < 2; ++sub) {
        lsum[sub] += __shfl_xor(lsum[sub], 16);
        lsum[sub] += __shfl_xor(lsum[sub], 32);
    }

    if (direct) {
#pragma unroll
        for (int sub = 0; sub < 2; ++sub)
#pragma unroll
            for (int r = 0; r < 4; ++r) {
                float lr = __shfl(lsum[sub], qd * 4 + r);
                float inv = 1.f / lr;
                size_t rowg = (size_t)(b * TT) + qbase + w * 32 + sub * 16 + qd * 4 + r;
#pragma unroll
                for (int nt = 0; nt < 4; ++nt)
                    out[rowg * 64 + nt * 16 + c] = o[sub][nt][r] * inv;
            }
    } else {
        const int slot = b * NCHUNK2 + cix;
        ushort* Od = Opart + (size_t)slot * 8192;
#pragma unroll
        for (int sub = 0; sub < 2; ++sub)
#pragma unroll
            for (int r = 0; r < 4; ++r) {
                int row = w * 32 + sub * 16 + qd * 4 + r;
#pragma unroll
                for (int nt = 0; nt < 4; ++nt)
                    Od[row * 64 + nt * 16 + c] = f2bf(o[sub][nt][r]);
            }
        if (qd == 0) {
            Ol[(size_t)slot * 128 + w * 32 + c] = lsum[0];
            Ol[(size_t)slot * 128 + w * 32 + 16 + c] = lsum[1];
        }
    }
}

// ---- Kernel 4: combine v2 — full MLP. 896 blocks (4 row-segments per tile);
// chunk loop unrolled to compile-time 8 with clamped index + mask so all 16
// loads per step are independent and in flight together. ----
__global__ __launch_bounds__(256) void combine_kernel(const ushort* __restrict__ Opart,
                                                      const float* __restrict__ Ol,
                                                      float* __restrict__ out) {
    const int bx = blockIdx.x;
    const int b = bx / 112;                 // 28 tiles x 4 segments
    const int rem = bx - b * 112;
    const int qq = 4 + (rem >> 2);          // 4..31
    const int seg = rem & 3;                // 32-row segment
    const int g = qq >> 2;                  // 1..7
    const int nch = g + 1;
    const int c0 = 2 * g * (g + 1) + (qq - 4 * g) * nch;
    const size_t slot0 = (size_t)(b * NCHUNK2 + c0);
    const int t = threadIdx.x;
    const int col = t & 63, r0 = t >> 6;

    for (int rr = 0; rr < 8; ++rr) {
        int row = seg * 32 + (rr << 2) + r0;
        float sv[8], av[8];
#pragma unroll
        for (int i = 0; i < 8; ++i) {
            int ii = (i < nch) ? i : 0;     // clamped: always a valid load
            sv[i] = Ol[(slot0 + ii) * 128 + row];
            av[i] = bf2f(Opart[(slot0 + ii) * 8192 + row * 64 + col]);
        }
        float S = 0.f, A = 0.f;
#pragma unroll
        for (int i = 0; i < 8; ++i) {
            float m = (i < nch) ? 1.f : 0.f;
            S += m * sv[i];
            A += m * av[i];
        }
        out[((size_t)(b * TT) + qq * 128 + row) * 64 + col] = A / S;
    }
}

extern "C" void kernel_launch(void* const* d_in, const int* in_sizes, int n_in,
                              void* d_out, int out_size, void* d_ws, size_t ws_size,
                              hipStream_t stream) {
    const float* x  = (const float*)d_in[0];
    const float* Wk = (const float*)d_in[1];
    const float* Wq = (const float*)d_in[2];
    const float* Wv = (const float*)d_in[3];
    float* out = (float*)d_out;

    // ws: q,k bf16 [32768][64]; v^T bf16 [8][64][4096]; Wt; bf16 partials + l
    ushort* qbuf = (ushort*)d_ws;
    ushort* kbuf = qbuf + (size_t)MROWS * 64;
    ushort* vbuf = kbuf + (size_t)MROWS * 64;
    ushort* wt   = vbuf + (size_t)MROWS * 64;
    const size_t base = (size_t)MROWS * 64 * 3 * 2 + (size_t)3 * 64 * CCH * 2;  // 12,877,824
    ushort* Opart = (ushort*)((char*)d_ws + base);
    float*  Ol    = (float*)((char*)d_ws + base + (size_t)BBA * NCHUNK2 * 8192 * 2);

    wt_kernel<<<36, 256, 0, stream>>>(Wq, Wk, Wv, wt);
    proj_kernel<<<MROWS / 64, 256, 0, stream>>>(x, wt, qbuf, kbuf, vbuf);
    attn_kernel<<<BBA * NCHUNK2, 256, 0, stream>>>(qbuf, kbuf, vbuf, out, Opart, Ol);
    combine_kernel<<<BBA * 112, 256, 0, stream>>>(Opart, Ol, out);
}